// Round 3
// baseline (528.175 us; speedup 1.0000x reference)
//
#include <hip/hip_runtime.h>
#include <math.h>

// Problem constants
#define N_TOK 131072   // 32*64*64 tokens
#define D     64       // embedding dim
#define K     1024     // codebook size

// Output layout (floats, concatenated in reference return order):
// [0 .. 8388607]              quantized_st  (N_TOK*D)
// [8388608]                   vq_loss
// [8388609 .. 8388609+131071] encoding_indices (as float)
// [8519681]                   perplexity
#define OUT_LOSS  8388608
#define OUT_IDX   8388609
#define OUT_PERP  8519681

// ws layout:
//   [0 .. 1023]   counts   (unsigned)
//   [1024..2047]  e_norms  (float)   -- bit-exact np.sum(w*w, axis=1)
//   [2048]        sse      (float)

// ---------------------------------------------------------------------------
// Bit-exact replica of numpy's pairwise sum for n=64 (base-case, 8
// accumulators; numpy's own comment: AVX auto-vectorization does not change
// this summation ordering). Input: 64 squared values.
// ---------------------------------------------------------------------------
__device__ __forceinline__ float np_pairsum64(const float* sq) {
    float r[8];
#pragma unroll
    for (int j = 0; j < 8; ++j) r[j] = sq[j];
#pragma unroll
    for (int i = 8; i < 64; i += 8) {
#pragma unroll
        for (int j = 0; j < 8; ++j) r[j] = __fadd_rn(r[j], sq[i + j]);
    }
    return __fadd_rn(
        __fadd_rn(__fadd_rn(r[0], r[1]), __fadd_rn(r[2], r[3])),
        __fadd_rn(__fadd_rn(r[4], r[5]), __fadd_rn(r[6], r[7])));
}

// ---------------------------------------------------------------------------
// Prep: per-code ||e||^2 exactly as np.sum(weight*weight, axis=1); zero ws.
// ---------------------------------------------------------------------------
__global__ void vq_prep(const float* __restrict__ w,
                        float* __restrict__ enorm,
                        unsigned* __restrict__ counts,
                        float* __restrict__ sse) {
    int k = blockIdx.x * blockDim.x + threadIdx.x;  // 4 blocks x 256
    if (k < K) {
        const float* wr = w + (size_t)k * D;
        float sq[D];
#pragma unroll
        for (int i = 0; i < D; ++i) sq[i] = __fmul_rn(wr[i], wr[i]);
        enorm[k] = np_pairsum64(sq);
        counts[k] = 0u;
    }
    if (k == 0) *sse = 0.f;
}

// ---------------------------------------------------------------------------
// Main: per-thread token. Bit-exact replica of the numpy fp32 computation:
//   dist[c] = fl( fl(Sx + Se[c]) - fl(2 * dot(x, e_c)) )
// with dot = sequential FMA over d ascending (OpenBLAS sgemm micro-kernel
// order: one accumulator per C element, k ascending, FMA).
// argmin: strict <, ascending c (first-min, np.argmin semantics).
// ---------------------------------------------------------------------------
__global__ __launch_bounds__(256, 4)
void vq_main(const float* __restrict__ x,
             const float* __restrict__ w,
             const float* __restrict__ enorm,
             float* __restrict__ out,
             unsigned* __restrict__ counts,
             float* __restrict__ sse) {
    int t = blockIdx.x * blockDim.x + threadIdx.x;
    if (t >= N_TOK) return;

    // Token row into registers.
    float xr[D];
    {
        const float4* xp = (const float4*)(x + (size_t)t * D);
#pragma unroll
        for (int i = 0; i < D / 4; ++i) {
            float4 v = xp[i];
            xr[4 * i + 0] = v.x;
            xr[4 * i + 1] = v.y;
            xr[4 * i + 2] = v.z;
            xr[4 * i + 3] = v.w;
        }
    }

    // Sx = np.sum(flat*flat, axis=1) bit-exact.
    float Sx;
    {
        float sq[D];
#pragma unroll
        for (int i = 0; i < D; ++i) sq[i] = __fmul_rn(xr[i], xr[i]);
        Sx = np_pairsum64(sq);
    }

    float best = INFINITY;
    int   bidx = 0;

    for (int c = 0; c < K; c += 4) {
        const float* __restrict__ w0 = w + (size_t)c * D;  // wave-uniform
        float a0 = 0.f, a1 = 0.f, a2 = 0.f, a3 = 0.f;
#pragma unroll
        for (int d = 0; d < D; ++d) {
            float xv = xr[d];
            a0 = __fmaf_rn(w0[0 * D + d], xv, a0);
            a1 = __fmaf_rn(w0[1 * D + d], xv, a1);
            a2 = __fmaf_rn(w0[2 * D + d], xv, a2);
            a3 = __fmaf_rn(w0[3 * D + d], xv, a3);
        }
        float t0 = __fadd_rn(Sx, enorm[c + 0]);
        float t1 = __fadd_rn(Sx, enorm[c + 1]);
        float t2 = __fadd_rn(Sx, enorm[c + 2]);
        float t3 = __fadd_rn(Sx, enorm[c + 3]);
        float dist0 = __fsub_rn(t0, __fmul_rn(2.0f, a0));
        float dist1 = __fsub_rn(t1, __fmul_rn(2.0f, a1));
        float dist2 = __fsub_rn(t2, __fmul_rn(2.0f, a2));
        float dist3 = __fsub_rn(t3, __fmul_rn(2.0f, a3));
        // first-min wins, ascending order
        bool l0 = dist0 < best; best = l0 ? dist0 : best; bidx = l0 ? c + 0 : bidx;
        bool l1 = dist1 < best; best = l1 ? dist1 : best; bidx = l1 ? c + 1 : bidx;
        bool l2 = dist2 < best; best = l2 ? dist2 : best; bidx = l2 ? c + 2 : bidx;
        bool l3 = dist3 < best; best = l3 ? dist3 : best; bidx = l3 ? c + 3 : bidx;
    }

    // Gather quantized row, write straight-through output, accumulate SSE.
    float err = 0.f;
    {
        const float4* qr = (const float4*)(w + (size_t)bidx * D);
        float4*       oq = (float4*)(out + (size_t)t * D);
#pragma unroll
        for (int i = 0; i < D / 4; ++i) {
            float4 q = qr[i];
            float dx0 = q.x - xr[4 * i + 0];
            float dx1 = q.y - xr[4 * i + 1];
            float dx2 = q.z - xr[4 * i + 2];
            float dx3 = q.w - xr[4 * i + 3];
            err = fmaf(dx0, dx0, err);
            err = fmaf(dx1, dx1, err);
            err = fmaf(dx2, dx2, err);
            err = fmaf(dx3, dx3, err);
            oq[i] = q;
        }
    }

    out[OUT_IDX + t] = (float)bidx;
    atomicAdd(&counts[bidx], 1u);

    // Wave-level reduce of err, one atomic per wave.
#pragma unroll
    for (int o = 32; o > 0; o >>= 1) err += __shfl_down(err, o, 64);
    if ((threadIdx.x & 63) == 0) atomicAdd(sse, err);
}

// ---------------------------------------------------------------------------
// Finalize: vq_loss and perplexity.
// ---------------------------------------------------------------------------
__global__ void vq_fin(const unsigned* __restrict__ counts,
                       const float* __restrict__ sse,
                       float* __restrict__ out) {
    __shared__ float red[256];
    float s = 0.f;
    for (int k = threadIdx.x; k < K; k += 256) {
        float p = (float)counts[k] * (1.0f / (float)N_TOK);
        s += p * logf(p + 1e-10f);
    }
    red[threadIdx.x] = s;
    __syncthreads();
    for (int st = 128; st > 0; st >>= 1) {
        if (threadIdx.x < st) red[threadIdx.x] += red[threadIdx.x + st];
        __syncthreads();
    }
    if (threadIdx.x == 0) {
        out[OUT_PERP] = expf(-red[0]);
        out[OUT_LOSS] = 1.25f * (*sse) * (1.0f / 8388608.0f);  // (1+0.25)*MSE
    }
}

// ---------------------------------------------------------------------------
extern "C" void kernel_launch(void* const* d_in, const int* in_sizes, int n_in,
                              void* d_out, int out_size, void* d_ws, size_t ws_size,
                              hipStream_t stream) {
    const float* x = (const float*)d_in[0];  // [32,64,64,64] fp32
    const float* w = (const float*)d_in[1];  // [1024,64] fp32
    float* out = (float*)d_out;

    unsigned* counts = (unsigned*)d_ws;
    float*    enorm  = (float*)d_ws + 1024;
    float*    sse    = (float*)d_ws + 2048;

    vq_prep<<<4, 256, 0, stream>>>(w, enorm, counts, sse);
    vq_main<<<N_TOK / 256, 256, 0, stream>>>(x, w, enorm, out, counts, sse);
    vq_fin<<<1, 256, 0, stream>>>(counts, sse, out);
}

// Round 4
// 525.447 us; speedup vs baseline: 1.0052x; 1.0052x over previous
//
#include <hip/hip_runtime.h>
#include <math.h>

// Problem constants
#define N_TOK 131072   // 32*64*64 tokens
#define D     64       // embedding dim
#define K     1024     // codebook size

// Output layout (floats, concatenated in reference return order):
#define OUT_LOSS  8388608
#define OUT_IDX   8388609
#define OUT_PERP  8519681

// ws layout: [0..1023] counts (unsigned) | [1024..2047] enorm (float) | [2048] sse

typedef float vf16 __attribute__((ext_vector_type(16)));

// ---------------------------------------------------------------------------
// Bit-exact replica of numpy's pairwise sum base case for n=64 (8 accumulators)
// ---------------------------------------------------------------------------
__device__ __forceinline__ float np_pairsum64(const float* sq) {
    float r[8];
#pragma unroll
    for (int j = 0; j < 8; ++j) r[j] = sq[j];
#pragma unroll
    for (int i = 8; i < 64; i += 8) {
#pragma unroll
        for (int j = 0; j < 8; ++j) r[j] = __fadd_rn(r[j], sq[i + j]);
    }
    return __fadd_rn(
        __fadd_rn(__fadd_rn(r[0], r[1]), __fadd_rn(r[2], r[3])),
        __fadd_rn(__fadd_rn(r[4], r[5]), __fadd_rn(r[6], r[7])));
}

// ---------------------------------------------------------------------------
// Prep: ||e||^2 bit-exact as np.sum(w*w, axis=1); zero counters/sse.
// (1024 threads total — perf-irrelevant, keep simple & correct.)
// ---------------------------------------------------------------------------
__global__ void vq_prep(const float* __restrict__ w,
                        float* __restrict__ enorm,
                        unsigned* __restrict__ counts,
                        float* __restrict__ sse) {
    int k = blockIdx.x * blockDim.x + threadIdx.x;
    if (k < K) {
        const float* wr = w + (size_t)k * D;
        float sq[D];
#pragma unroll
        for (int i = 0; i < D; ++i) sq[i] = __fmul_rn(wr[i], wr[i]);
        enorm[k] = np_pairsum64(sq);
        counts[k] = 0u;
    }
    if (k == 0) *sse = 0.f;
}

// ---------------------------------------------------------------------------
// Main: thread = token. Token row lives in 4 ext-vectors (SSA, register-only).
// dist[c] = fl( fl(Sx + Se[c]) - fl(2 * seqFMA_dot(x, e_c)) ), first-min scan.
// ---------------------------------------------------------------------------
// Compile-time-constant component access into the 4 row vectors.
#define XR(d) ((d) < 16 ? xa[(d) & 15] : (d) < 32 ? xb[(d) & 15] \
              : (d) < 48 ? xc[(d) & 15] : xd[(d) & 15])

__global__ __launch_bounds__(256, 1)
void vq_main(const float* __restrict__ x,
             const float* __restrict__ w,
             const float* __restrict__ enorm,
             float* __restrict__ out,
             unsigned* __restrict__ counts,
             float* __restrict__ sse) {
    int t = blockIdx.x * blockDim.x + threadIdx.x;
    if (t >= N_TOK) return;

    const vf16* xp = (const vf16*)(x + (size_t)t * D);
    vf16 xa = xp[0], xb = xp[1], xc = xp[2], xd = xp[3];

    // Sx = np.sum(x*x) bit-exact: 8 accumulators, adds in ascending-i order.
    float Sx;
    {
        float r0, r1, r2, r3, r4, r5, r6, r7;
#define SQ(n) __fmul_rn(XR(n), XR(n))
        r0 = SQ(0); r1 = SQ(1); r2 = SQ(2); r3 = SQ(3);
        r4 = SQ(4); r5 = SQ(5); r6 = SQ(6); r7 = SQ(7);
#define ACC8(i)                                                     \
        r0 = __fadd_rn(r0, SQ(8*(i)+0)); r1 = __fadd_rn(r1, SQ(8*(i)+1)); \
        r2 = __fadd_rn(r2, SQ(8*(i)+2)); r3 = __fadd_rn(r3, SQ(8*(i)+3)); \
        r4 = __fadd_rn(r4, SQ(8*(i)+4)); r5 = __fadd_rn(r5, SQ(8*(i)+5)); \
        r6 = __fadd_rn(r6, SQ(8*(i)+6)); r7 = __fadd_rn(r7, SQ(8*(i)+7));
        ACC8(1) ACC8(2) ACC8(3) ACC8(4) ACC8(5) ACC8(6) ACC8(7)
        Sx = __fadd_rn(
            __fadd_rn(__fadd_rn(r0, r1), __fadd_rn(r2, r3)),
            __fadd_rn(__fadd_rn(r4, r5), __fadd_rn(r6, r7)));
#undef ACC8
#undef SQ
    }

    float best = INFINITY;
    int   bidx = 0;

    for (int c = 0; c < K; c += 4) {
        const float* __restrict__ wr = w + (size_t)c * D;  // wave-uniform
        float a0 = 0.f, a1 = 0.f, a2 = 0.f, a3 = 0.f;
#pragma unroll
        for (int d = 0; d < D; ++d) {
            float xv = XR(d);
            a0 = __fmaf_rn(wr[0 * D + d], xv, a0);
            a1 = __fmaf_rn(wr[1 * D + d], xv, a1);
            a2 = __fmaf_rn(wr[2 * D + d], xv, a2);
            a3 = __fmaf_rn(wr[3 * D + d], xv, a3);
        }
        float d0 = __fsub_rn(__fadd_rn(Sx, enorm[c + 0]), __fmul_rn(2.0f, a0));
        float d1 = __fsub_rn(__fadd_rn(Sx, enorm[c + 1]), __fmul_rn(2.0f, a1));
        float d2 = __fsub_rn(__fadd_rn(Sx, enorm[c + 2]), __fmul_rn(2.0f, a2));
        float d3 = __fsub_rn(__fadd_rn(Sx, enorm[c + 3]), __fmul_rn(2.0f, a3));
        bool l0 = d0 < best; best = l0 ? d0 : best; bidx = l0 ? c + 0 : bidx;
        bool l1 = d1 < best; best = l1 ? d1 : best; bidx = l1 ? c + 1 : bidx;
        bool l2 = d2 < best; best = l2 ? d2 : best; bidx = l2 ? c + 2 : bidx;
        bool l3 = d3 < best; best = l3 ? d3 : best; bidx = l3 ? c + 3 : bidx;
    }

    // Gather winner row, write straight-through output, accumulate SSE.
    float err = 0.f;
    {
        const float4* qr = (const float4*)(w + (size_t)bidx * D);
        float4*       oq = (float4*)(out + (size_t)t * D);
#pragma unroll
        for (int i = 0; i < 16; ++i) {
            float4 q = qr[i];
            float e0 = q.x - XR(4 * i + 0);
            float e1 = q.y - XR(4 * i + 1);
            float e2 = q.z - XR(4 * i + 2);
            float e3 = q.w - XR(4 * i + 3);
            err = fmaf(e0, e0, err);
            err = fmaf(e1, e1, err);
            err = fmaf(e2, e2, err);
            err = fmaf(e3, e3, err);
            oq[i] = q;
        }
    }

    out[OUT_IDX + t] = (float)bidx;
    atomicAdd(&counts[bidx], 1u);

#pragma unroll
    for (int o = 32; o > 0; o >>= 1) err += __shfl_down(err, o, 64);
    if ((threadIdx.x & 63) == 0) atomicAdd(sse, err);
}
#undef XR

// ---------------------------------------------------------------------------
// Finalize: vq_loss and perplexity.
// ---------------------------------------------------------------------------
__global__ void vq_fin(const unsigned* __restrict__ counts,
                       const float* __restrict__ sse,
                       float* __restrict__ out) {
    __shared__ float red[256];
    float s = 0.f;
    for (int k = threadIdx.x; k < K; k += 256) {
        float p = (float)counts[k] * (1.0f / (float)N_TOK);
        s += p * logf(p + 1e-10f);
    }
    red[threadIdx.x] = s;
    __syncthreads();
    for (int st = 128; st > 0; st >>= 1) {
        if (threadIdx.x < st) red[threadIdx.x] += red[threadIdx.x + st];
        __syncthreads();
    }
    if (threadIdx.x == 0) {
        out[OUT_PERP] = expf(-red[0]);
        out[OUT_LOSS] = 1.25f * (*sse) * (1.0f / 8388608.0f);  // (1+0.25)*MSE
    }
}

// ---------------------------------------------------------------------------
extern "C" void kernel_launch(void* const* d_in, const int* in_sizes, int n_in,
                              void* d_out, int out_size, void* d_ws, size_t ws_size,
                              hipStream_t stream) {
    const float* x = (const float*)d_in[0];  // [32,64,64,64] fp32
    const float* w = (const float*)d_in[1];  // [1024,64] fp32
    float* out = (float*)d_out;

    unsigned* counts = (unsigned*)d_ws;
    float*    enorm  = (float*)d_ws + 1024;
    float*    sse    = (float*)d_ws + 2048;

    vq_prep<<<4, 256, 0, stream>>>(w, enorm, counts, sse);
    vq_main<<<N_TOK / 256, 256, 0, stream>>>(x, w, enorm, out, counts, sse);
    vq_fin<<<1, 256, 0, stream>>>(counts, sse, out);
}

// Round 5
// 374.952 us; speedup vs baseline: 1.4086x; 1.4014x over previous
//
#include <hip/hip_runtime.h>
#include <math.h>

// Problem constants
#define N_TOK 131072   // 32*64*64 tokens
#define D     64       // embedding dim
#define K     1024     // codebook size

// Output layout (floats, concatenated in reference return order):
#define OUT_LOSS  8388608
#define OUT_IDX   8388609
#define OUT_PERP  8519681

// ws layout: [0..1023] counts (unsigned) | [1024..2047] enorm (float) | [2048] sse

typedef float vf16 __attribute__((ext_vector_type(16)));

// ---------------------------------------------------------------------------
// Bit-exact replica of numpy's pairwise sum base case for n=64 (8 accumulators)
// ---------------------------------------------------------------------------
__device__ __forceinline__ float np_pairsum64(const float* sq) {
    float r[8];
#pragma unroll
    for (int j = 0; j < 8; ++j) r[j] = sq[j];
#pragma unroll
    for (int i = 8; i < 64; i += 8) {
#pragma unroll
        for (int j = 0; j < 8; ++j) r[j] = __fadd_rn(r[j], sq[i + j]);
    }
    return __fadd_rn(
        __fadd_rn(__fadd_rn(r[0], r[1]), __fadd_rn(r[2], r[3])),
        __fadd_rn(__fadd_rn(r[4], r[5]), __fadd_rn(r[6], r[7])));
}

// ---------------------------------------------------------------------------
// Prep: ||e||^2 bit-exact as np.sum(w*w, axis=1); zero counters/sse.
// ---------------------------------------------------------------------------
__global__ void vq_prep(const float* __restrict__ w,
                        float* __restrict__ enorm,
                        unsigned* __restrict__ counts,
                        float* __restrict__ sse) {
    int k = blockIdx.x * blockDim.x + threadIdx.x;
    if (k < K) {
        const float* wr = w + (size_t)k * D;
        float sq[D];
#pragma unroll
        for (int i = 0; i < D; ++i) sq[i] = __fmul_rn(wr[i], wr[i]);
        enorm[k] = np_pairsum64(sq);
        counts[k] = 0u;
    }
    if (k == 0) *sse = 0.f;
}

// ---------------------------------------------------------------------------
// Main. Block = 256 threads = 4 waves. token = blockIdx*64 + lane;
// wave j screens codes [256j, 256j+256) (w pointers wave-uniform -> SGPR).
// LDS combine (first-min, chunks ascending == indices ascending) then wave 0
// does the gather/write/SSE epilogue.
// dist[c] = fl( fl(Sx + Se[c]) - fl(2 * seqFMA_dot(x, e_c)) )  -- bit-exact.
// ---------------------------------------------------------------------------
#define XR(d) ((d) < 16 ? xa[(d) & 15] : (d) < 32 ? xb[(d) & 15] \
              : (d) < 48 ? xc[(d) & 15] : xd[(d) & 15])

__global__ __launch_bounds__(256, 1)
void vq_main(const float* __restrict__ x,
             const float* __restrict__ w,
             const float* __restrict__ enorm,
             float* __restrict__ out,
             unsigned* __restrict__ counts,
             float* __restrict__ sse) {
    const int lane  = threadIdx.x & 63;
    const int chunk = __builtin_amdgcn_readfirstlane(threadIdx.x >> 6);
    const int t     = blockIdx.x * 64 + lane;

    // Token row in 4 SSA vectors (64 VGPRs).
    const vf16* xp = (const vf16*)(x + (size_t)t * D);
    vf16 xa = xp[0], xb = xp[1], xc = xp[2], xd = xp[3];

    // Sx = np.sum(x*x) bit-exact: 8 accumulators, ascending blocks, pairwise tail.
    float Sx;
    {
        float r0, r1, r2, r3, r4, r5, r6, r7;
#define SQ(n) __fmul_rn(XR(n), XR(n))
        r0 = SQ(0); r1 = SQ(1); r2 = SQ(2); r3 = SQ(3);
        r4 = SQ(4); r5 = SQ(5); r6 = SQ(6); r7 = SQ(7);
#define ACC8(i)                                                           \
        r0 = __fadd_rn(r0, SQ(8*(i)+0)); r1 = __fadd_rn(r1, SQ(8*(i)+1)); \
        r2 = __fadd_rn(r2, SQ(8*(i)+2)); r3 = __fadd_rn(r3, SQ(8*(i)+3)); \
        r4 = __fadd_rn(r4, SQ(8*(i)+4)); r5 = __fadd_rn(r5, SQ(8*(i)+5)); \
        r6 = __fadd_rn(r6, SQ(8*(i)+6)); r7 = __fadd_rn(r7, SQ(8*(i)+7));
        ACC8(1) ACC8(2) ACC8(3) ACC8(4) ACC8(5) ACC8(6) ACC8(7)
        Sx = __fadd_rn(
            __fadd_rn(__fadd_rn(r0, r1), __fadd_rn(r2, r3)),
            __fadd_rn(__fadd_rn(r4, r5), __fadd_rn(r6, r7)));
#undef ACC8
#undef SQ
    }

    // Screen this wave's 256-code chunk.
    float best = INFINITY;
    int   bidx = 0;
    const int c0 = chunk << 8;

    for (int cc = 0; cc < 256; cc += 4) {
        const float* __restrict__ wr = w + (size_t)(c0 + cc) * D;  // wave-uniform
        float a0 = 0.f, a1 = 0.f, a2 = 0.f, a3 = 0.f;
#pragma unroll
        for (int d = 0; d < D; ++d) {
            float xv = XR(d);
            a0 = __fmaf_rn(wr[0 * D + d], xv, a0);
            a1 = __fmaf_rn(wr[1 * D + d], xv, a1);
            a2 = __fmaf_rn(wr[2 * D + d], xv, a2);
            a3 = __fmaf_rn(wr[3 * D + d], xv, a3);
        }
        int c = c0 + cc;
        float d0 = __fsub_rn(__fadd_rn(Sx, enorm[c + 0]), __fmul_rn(2.0f, a0));
        float d1 = __fsub_rn(__fadd_rn(Sx, enorm[c + 1]), __fmul_rn(2.0f, a1));
        float d2 = __fsub_rn(__fadd_rn(Sx, enorm[c + 2]), __fmul_rn(2.0f, a2));
        float d3 = __fsub_rn(__fadd_rn(Sx, enorm[c + 3]), __fmul_rn(2.0f, a3));
        bool l0 = d0 < best; best = l0 ? d0 : best; bidx = l0 ? c + 0 : bidx;
        bool l1 = d1 < best; best = l1 ? d1 : best; bidx = l1 ? c + 1 : bidx;
        bool l2 = d2 < best; best = l2 ? d2 : best; bidx = l2 ? c + 2 : bidx;
        bool l3 = d3 < best; best = l3 ? d3 : best; bidx = l3 ? c + 3 : bidx;
    }

    // Combine the 4 chunk winners per token (chunk order == index order).
    __shared__ float sdist[4][64];
    __shared__ int   sidx[4][64];
    sdist[chunk][lane] = best;
    sidx[chunk][lane]  = bidx;
    __syncthreads();

    if (threadIdx.x < 64) {
        float b  = sdist[0][lane];
        int   bi = sidx[0][lane];
#pragma unroll
        for (int j = 1; j < 4; ++j) {
            float dj = sdist[j][lane];
            bool  l  = dj < b;   // strict <: lower chunk (lower index) wins ties
            b  = l ? dj : b;
            bi = l ? sidx[j][lane] : bi;
        }

        // Epilogue: gather winner row, write quantized + index, accumulate SSE.
        float err = 0.f;
        const float4* qr = (const float4*)(w + (size_t)bi * D);
        float4*       oq = (float4*)(out + (size_t)t * D);
#pragma unroll
        for (int i = 0; i < 16; ++i) {
            float4 q = qr[i];
            float e0 = q.x - XR(4 * i + 0);
            float e1 = q.y - XR(4 * i + 1);
            float e2 = q.z - XR(4 * i + 2);
            float e3 = q.w - XR(4 * i + 3);
            err = fmaf(e0, e0, err);
            err = fmaf(e1, e1, err);
            err = fmaf(e2, e2, err);
            err = fmaf(e3, e3, err);
            oq[i] = q;
        }

        out[OUT_IDX + t] = (float)bi;
        atomicAdd(&counts[bi], 1u);

#pragma unroll
        for (int o = 32; o > 0; o >>= 1) err += __shfl_down(err, o, 64);
        if (lane == 0) atomicAdd(sse, err);
    }
}
#undef XR

// ---------------------------------------------------------------------------
// Finalize: vq_loss and perplexity.
// ---------------------------------------------------------------------------
__global__ void vq_fin(const unsigned* __restrict__ counts,
                       const float* __restrict__ sse,
                       float* __restrict__ out) {
    __shared__ float red[256];
    float s = 0.f;
    for (int k = threadIdx.x; k < K; k += 256) {
        float p = (float)counts[k] * (1.0f / (float)N_TOK);
        s += p * logf(p + 1e-10f);
    }
    red[threadIdx.x] = s;
    __syncthreads();
    for (int st = 128; st > 0; st >>= 1) {
        if (threadIdx.x < st) red[threadIdx.x] += red[threadIdx.x + st];
        __syncthreads();
    }
    if (threadIdx.x == 0) {
        out[OUT_PERP] = expf(-red[0]);
        out[OUT_LOSS] = 1.25f * (*sse) * (1.0f / 8388608.0f);  // (1+0.25)*MSE
    }
}

// ---------------------------------------------------------------------------
extern "C" void kernel_launch(void* const* d_in, const int* in_sizes, int n_in,
                              void* d_out, int out_size, void* d_ws, size_t ws_size,
                              hipStream_t stream) {
    const float* x = (const float*)d_in[0];  // [32,64,64,64] fp32
    const float* w = (const float*)d_in[1];  // [1024,64] fp32
    float* out = (float*)d_out;

    unsigned* counts = (unsigned*)d_ws;
    float*    enorm  = (float*)d_ws + 1024;
    float*    sse    = (float*)d_ws + 2048;

    vq_prep<<<4, 256, 0, stream>>>(w, enorm, counts, sse);
    vq_main<<<N_TOK / 64, 256, 0, stream>>>(x, w, enorm, out, counts, sse);
    vq_fin<<<1, 256, 0, stream>>>(counts, sse, out);
}

// Round 6
// 349.374 us; speedup vs baseline: 1.5118x; 1.0732x over previous
//
#include <hip/hip_runtime.h>
#include <math.h>

// Problem constants
#define N_TOK 131072   // 32*64*64 tokens
#define D     64       // embedding dim
#define K     1024     // codebook size

// Output layout (floats, concatenated in reference return order):
#define OUT_LOSS  8388608
#define OUT_IDX   8388609
#define OUT_PERP  8519681

// ws layout (bytes):
//   0       counts   u32[1024]
//   4096    enorm    f32[1024]   np-exact ||e||^2 (pairwise sum)
//   8192    sinit    f32[1024]   fp64-accurate ||e||^2 (screen C-init)
//   12288   sse      f32
//   16384   w_hi     s16[65536]  bf16 hi split of w (128 KB)
//   147456  w_lo     s16[65536]  bf16 lo split of w (128 KB)

#define W_WINDOW 1e-4f

typedef short bf16x8 __attribute__((ext_vector_type(8)));
typedef float f32x4  __attribute__((ext_vector_type(4)));

// ---------------------------------------------------------------------------
// np pairwise-sum base case for n=64 (8 accumulators) — bit-exact vs numpy.
// ---------------------------------------------------------------------------
__device__ __forceinline__ float np_pairsum64(const float* sq) {
    float r[8];
#pragma unroll
    for (int j = 0; j < 8; ++j) r[j] = sq[j];
#pragma unroll
    for (int i = 8; i < 64; i += 8) {
#pragma unroll
        for (int j = 0; j < 8; ++j) r[j] = __fadd_rn(r[j], sq[i + j]);
    }
    return __fadd_rn(
        __fadd_rn(__fadd_rn(r[0], r[1]), __fadd_rn(r[2], r[3])),
        __fadd_rn(__fadd_rn(r[4], r[5]), __fadd_rn(r[6], r[7])));
}

__device__ __forceinline__ short bf16_trunc(float f) {
    return (short)(__float_as_uint(f) >> 16);
}
__device__ __forceinline__ float bf16_up(short s) {
    return __uint_as_float(((unsigned)(unsigned short)s) << 16);
}

// ---------------------------------------------------------------------------
// Prep: enorm (np-exact), sinit (fp64-accurate), bf16 splits of w, zero ws.
// ---------------------------------------------------------------------------
__global__ void vq_prep(const float* __restrict__ w,
                        float* __restrict__ enorm,
                        float* __restrict__ sinit,
                        short* __restrict__ w_hi,
                        short* __restrict__ w_lo,
                        unsigned* __restrict__ counts,
                        float* __restrict__ sse) {
    int k = blockIdx.x * blockDim.x + threadIdx.x;
    if (k < K) {
        const float* wr = w + (size_t)k * D;
        float sq[D];
        double acc = 0.0;
#pragma unroll
        for (int i = 0; i < D; ++i) {
            float v = wr[i];
            sq[i] = __fmul_rn(v, v);
            acc += (double)v * (double)v;
            short hi = bf16_trunc(v);
            float res = v - bf16_up(hi);
            short lo = bf16_trunc(res);
            w_hi[(size_t)k * D + i] = hi;
            w_lo[(size_t)k * D + i] = lo;
        }
        enorm[k] = np_pairsum64(sq);
        sinit[k] = (float)acc;
        counts[k] = 0u;
    }
    if (k == 0) *sse = 0.f;
}

// ---------------------------------------------------------------------------
// Screen kernel. Block = 256 threads = 4 waves; block covers 128 tokens
// (wave -> 32 tokens = 2 M-tiles of 16). MFMA 16x16x32 bf16, split-precision:
//   score(c) = Se_acc(c) + (-2x).e  via hi*hi + hi*lo + lo*hi  (err ~1e-6)
// Pass 1: per-token screen min. Pass 2: identical recompute, collect all
// candidates <= min + W into LDS. Rescue: np-exact fp32 chain on candidates.
// ---------------------------------------------------------------------------
#define MFMA(A, B, C) __builtin_amdgcn_mfma_f32_16x16x32_bf16(A, B, C, 0, 0, 0)

__global__ __launch_bounds__(256, 1)
void vq_screen(const float* __restrict__ x,
               const float* __restrict__ w,
               const float* __restrict__ enorm,
               const float* __restrict__ sinit,
               const short* __restrict__ w_hi,
               const short* __restrict__ w_lo,
               float* __restrict__ out,
               unsigned* __restrict__ counts,
               float* __restrict__ sse) {
    const int lane = threadIdx.x & 63;
    const int wv   = threadIdx.x >> 6;   // 0..3
    const int quad = lane >> 4;          // 0..3
    const int col  = lane & 15;

    const int tokBlock = blockIdx.x * 128;
    const int tokWave  = tokBlock + wv * 32;

    // --- A fragments: bf16 hi/lo splits of (-2 * x) ---------------------
    // A[m = lane&15][k = quad*8 + j], k-tile ks covers k in [ks*32, ks*32+32)
    bf16x8 Ah[2][2], Al[2][2];
#pragma unroll
    for (int mt = 0; mt < 2; ++mt) {
#pragma unroll
        for (int ks = 0; ks < 2; ++ks) {
            const float4* ap = (const float4*)(x + (size_t)(tokWave + mt * 16 + col) * D
                                               + ks * 32 + quad * 8);
            float4 u0 = ap[0], u1 = ap[1];
            float f[8] = {u0.x, u0.y, u0.z, u0.w, u1.x, u1.y, u1.z, u1.w};
            bf16x8 h, l;
#pragma unroll
            for (int j = 0; j < 8; ++j) {
                float v = -2.0f * f[j];
                short hi = bf16_trunc(v);
                float res = v - bf16_up(hi);
                h[j] = hi;
                l[j] = bf16_trunc(res);
            }
            Ah[mt][ks] = h;
            Al[mt][ks] = l;
        }
    }

    // --- Pass 1: per-lane running min over 64 code tiles ----------------
    float m0[4] = {INFINITY, INFINITY, INFINITY, INFINITY};
    float m1[4] = {INFINITY, INFINITY, INFINITY, INFINITY};

#pragma unroll 4
    for (int tile = 0; tile < 64; ++tile) {
        const int cbase = tile * 16;
        const size_t rowoff = (size_t)(cbase + col) * D;
        bf16x8 Bh0 = *(const bf16x8*)(w_hi + rowoff + 0 * 32 + quad * 8);
        bf16x8 Bh1 = *(const bf16x8*)(w_hi + rowoff + 1 * 32 + quad * 8);
        bf16x8 Bl0 = *(const bf16x8*)(w_lo + rowoff + 0 * 32 + quad * 8);
        bf16x8 Bl1 = *(const bf16x8*)(w_lo + rowoff + 1 * 32 + quad * 8);
        float si = sinit[cbase + col];
        f32x4 C0 = {si, si, si, si};
        f32x4 C1 = {si, si, si, si};
        C0 = MFMA(Ah[0][0], Bh0, C0); C0 = MFMA(Ah[0][1], Bh1, C0);
        C0 = MFMA(Ah[0][0], Bl0, C0); C0 = MFMA(Ah[0][1], Bl1, C0);
        C0 = MFMA(Al[0][0], Bh0, C0); C0 = MFMA(Al[0][1], Bh1, C0);
        C1 = MFMA(Ah[1][0], Bh0, C1); C1 = MFMA(Ah[1][1], Bh1, C1);
        C1 = MFMA(Ah[1][0], Bl0, C1); C1 = MFMA(Ah[1][1], Bl1, C1);
        C1 = MFMA(Al[1][0], Bh0, C1); C1 = MFMA(Al[1][1], Bh1, C1);
#pragma unroll
        for (int r = 0; r < 4; ++r) {
            m0[r] = fminf(m0[r], C0[r]);
            m1[r] = fminf(m1[r], C1[r]);
        }
    }

    // Cross-lane min over the 16 lanes of each quad (rows quad*4+r).
#pragma unroll
    for (int r = 0; r < 4; ++r) {
#pragma unroll
        for (int msk = 1; msk <= 8; msk <<= 1) {
            m0[r] = fminf(m0[r], __shfl_xor(m0[r], msk, 64));
            m1[r] = fminf(m1[r], __shfl_xor(m1[r], msk, 64));
        }
        m0[r] += W_WINDOW;
        m1[r] += W_WINDOW;
    }

    // --- Candidate lists in LDS ----------------------------------------
    __shared__ unsigned cnt[128];
    __shared__ unsigned slots[128][7];
    if (threadIdx.x < 128) cnt[threadIdx.x] = 0u;
    __syncthreads();

    // --- Pass 2: identical recompute, collect candidates <= min + W -----
#pragma unroll 4
    for (int tile = 0; tile < 64; ++tile) {
        const int cbase = tile * 16;
        const size_t rowoff = (size_t)(cbase + col) * D;
        bf16x8 Bh0 = *(const bf16x8*)(w_hi + rowoff + 0 * 32 + quad * 8);
        bf16x8 Bh1 = *(const bf16x8*)(w_hi + rowoff + 1 * 32 + quad * 8);
        bf16x8 Bl0 = *(const bf16x8*)(w_lo + rowoff + 0 * 32 + quad * 8);
        bf16x8 Bl1 = *(const bf16x8*)(w_lo + rowoff + 1 * 32 + quad * 8);
        float si = sinit[cbase + col];
        f32x4 C0 = {si, si, si, si};
        f32x4 C1 = {si, si, si, si};
        C0 = MFMA(Ah[0][0], Bh0, C0); C0 = MFMA(Ah[0][1], Bh1, C0);
        C0 = MFMA(Ah[0][0], Bl0, C0); C0 = MFMA(Ah[0][1], Bl1, C0);
        C0 = MFMA(Al[0][0], Bh0, C0); C0 = MFMA(Al[0][1], Bh1, C0);
        C1 = MFMA(Ah[1][0], Bh0, C1); C1 = MFMA(Ah[1][1], Bh1, C1);
        C1 = MFMA(Ah[1][0], Bl0, C1); C1 = MFMA(Ah[1][1], Bl1, C1);
        C1 = MFMA(Al[1][0], Bh0, C1); C1 = MFMA(Al[1][1], Bh1, C1);
#pragma unroll
        for (int r = 0; r < 4; ++r) {
            if (C0[r] <= m0[r]) {
                unsigned tl = wv * 32 + 0 * 16 + quad * 4 + r;
                unsigned s = atomicAdd(&cnt[tl], 1u);
                if (s < 7u) slots[tl][s] = cbase + col;
            }
            if (C1[r] <= m1[r]) {
                unsigned tl = wv * 32 + 1 * 16 + quad * 4 + r;
                unsigned s = atomicAdd(&cnt[tl], 1u);
                if (s < 7u) slots[tl][s] = cbase + col;
            }
        }
    }
    __syncthreads();

    // --- Rescue (np-exact fp32 chain on multi-candidate tokens) + epilogue
    if (threadIdx.x < 128) {
        const int tl = threadIdx.x;
        const int t  = tokBlock + tl;
        unsigned n = cnt[tl];
        int winner = (n > 0u) ? (int)slots[tl][0] : 0;

        if (n > 1u) {
            // np-exact: Sx (pairwise), then dist = fl(fl(Sx+Se) - fl(2*dot))
            float xr[D];
            const float4* xp = (const float4*)(x + (size_t)t * D);
#pragma unroll
            for (int i = 0; i < 16; ++i) {
                float4 v = xp[i];
                xr[4 * i + 0] = v.x; xr[4 * i + 1] = v.y;
                xr[4 * i + 2] = v.z; xr[4 * i + 3] = v.w;
            }
            float sq[D];
#pragma unroll
            for (int i = 0; i < D; ++i) sq[i] = __fmul_rn(xr[i], xr[i]);
            float Sx = np_pairsum64(sq);

            float bestd = INFINITY;
            int   bestc = -1;
            unsigned m = n < 7u ? n : 7u;
            for (unsigned i = 0; i < m; ++i) {
                int c = (int)slots[tl][i];
                const float* wr = w + (size_t)c * D;
                float a = 0.f;
#pragma unroll
                for (int d = 0; d < D; ++d) a = __fmaf_rn(wr[d], xr[d], a);
                float dist = __fsub_rn(__fadd_rn(Sx, enorm[c]), __fmul_rn(2.0f, a));
                if (dist < bestd || (dist == bestd && c < bestc)) {
                    bestd = dist; bestc = c;
                }
            }
            winner = bestc;
        }

        // Epilogue: quantized write + SSE + counts + index.
        float err = 0.f;
        const float4* qr = (const float4*)(w + (size_t)winner * D);
        const float4* xp2 = (const float4*)(x + (size_t)t * D);
        float4*       oq = (float4*)(out + (size_t)t * D);
#pragma unroll
        for (int i = 0; i < 16; ++i) {
            float4 q = qr[i];
            float4 xv = xp2[i];
            float e0 = q.x - xv.x, e1 = q.y - xv.y;
            float e2 = q.z - xv.z, e3 = q.w - xv.w;
            err = fmaf(e0, e0, err);
            err = fmaf(e1, e1, err);
            err = fmaf(e2, e2, err);
            err = fmaf(e3, e3, err);
            oq[i] = q;
        }
        out[OUT_IDX + t] = (float)winner;
        atomicAdd(&counts[winner], 1u);

#pragma unroll
        for (int o = 32; o > 0; o >>= 1) err += __shfl_down(err, o, 64);
        if ((threadIdx.x & 63) == 0) atomicAdd(sse, err);
    }
}

// ---------------------------------------------------------------------------
// Finalize: vq_loss and perplexity.
// ---------------------------------------------------------------------------
__global__ void vq_fin(const unsigned* __restrict__ counts,
                       const float* __restrict__ sse,
                       float* __restrict__ out) {
    __shared__ float red[256];
    float s = 0.f;
    for (int k = threadIdx.x; k < K; k += 256) {
        float p = (float)counts[k] * (1.0f / (float)N_TOK);
        s += p * logf(p + 1e-10f);
    }
    red[threadIdx.x] = s;
    __syncthreads();
    for (int st = 128; st > 0; st >>= 1) {
        if (threadIdx.x < st) red[threadIdx.x] += red[threadIdx.x + st];
        __syncthreads();
    }
    if (threadIdx.x == 0) {
        out[OUT_PERP] = expf(-red[0]);
        out[OUT_LOSS] = 1.25f * (*sse) * (1.0f / 8388608.0f);  // (1+0.25)*MSE
    }
}

// ---------------------------------------------------------------------------
extern "C" void kernel_launch(void* const* d_in, const int* in_sizes, int n_in,
                              void* d_out, int out_size, void* d_ws, size_t ws_size,
                              hipStream_t stream) {
    const float* x = (const float*)d_in[0];  // [32,64,64,64] fp32
    const float* w = (const float*)d_in[1];  // [1024,64] fp32
    float* out = (float*)d_out;

    char* ws = (char*)d_ws;
    unsigned* counts = (unsigned*)(ws + 0);
    float*    enorm  = (float*)(ws + 4096);
    float*    sinit  = (float*)(ws + 8192);
    float*    sse    = (float*)(ws + 12288);
    short*    w_hi   = (short*)(ws + 16384);
    short*    w_lo   = (short*)(ws + 147456);

    vq_prep<<<4, 256, 0, stream>>>(w, enorm, sinit, w_hi, w_lo, counts, sse);
    vq_screen<<<N_TOK / 128, 256, 0, stream>>>(x, w, enorm, sinit, w_hi, w_lo,
                                               out, counts, sse);
    vq_fin<<<1, 256, 0, stream>>>(counts, sse, out);
}